// Round 6
// baseline (499.129 us; speedup 1.0000x reference)
//
#include <hip/hip_runtime.h>

typedef float  f32x4  __attribute__((ext_vector_type(4)));
typedef __bf16 bf16x8 __attribute__((ext_vector_type(8)));
typedef unsigned short u16x8 __attribute__((ext_vector_type(8)));
typedef unsigned short u16x4 __attribute__((ext_vector_type(4)));

#define DEV static __device__ __forceinline__

DEV unsigned short f2b(float f) {            // f32 -> bf16 (RNE)
  unsigned int u = __float_as_uint(f);
  u += 0x7fffu + ((u >> 16) & 1u);
  return (unsigned short)(u >> 16);
}
DEV float b2f(unsigned short h) { return __uint_as_float(((unsigned int)h) << 16); }

DEV f32x4 mfma16(bf16x8 a, bf16x8 b, f32x4 c) {
  return __builtin_amdgcn_mfma_f32_16x16x32_bf16(a, b, c, 0, 0, 0);
}

typedef __attribute__((address_space(1))) const unsigned int* gas_t;
typedef __attribute__((address_space(3))) unsigned int* las_t;
DEV void gl16(const void* g, void* l) {      // 16B global -> LDS (dest: base + lane*16)
  __builtin_amdgcn_global_load_lds((gas_t)g, (las_t)l, 16, 0, 0);
}

// ---------------------------------------------------------------- prep
__global__ __launch_bounds__(256) void k_prep(
    const float* __restrict__ Wq_comp, const float* __restrict__ Wkv_comp,
    const float* __restrict__ Wqc, const float* __restrict__ Wqr,
    const float* __restrict__ Wkc, const float* __restrict__ Wkr,
    const float* __restrict__ Wv,
    unsigned short* __restrict__ W1t, unsigned short* __restrict__ Wqt,
    unsigned short* __restrict__ Wkvt, float* __restrict__ ct, float* __restrict__ st) {
  int tid = blockIdx.x * 256 + threadIdx.x;
  if (tid < 131072) {                       // W1t
    int n = tid >> 8, k = tid & 255;
    float v = (n < 256) ? Wq_comp[k * 256 + n] : Wkv_comp[k * 256 + (n - 256)];
    W1t[tid] = f2b(v);
  } else if (tid < 196608) {                // Wqt
    int t2 = tid - 131072; int n = t2 >> 8, k = t2 & 255;
    float v = (n < 192) ? Wqc[k * 192 + n] : Wqr[k * 64 + (n - 192)];
    Wqt[t2] = f2b(v);
  } else if (tid < 327680) {                // Wkvt
    int t2 = tid - 196608; int n = t2 >> 8, k = t2 & 255;
    float v = (n < 192) ? Wkc[k * 192 + n]
             : (n < 256) ? Wkr[k * 64 + (n - 192)] : Wv[k * 256 + (n - 256)];
    Wkvt[t2] = f2b(v);
  } else if (tid < 393216) {                // rope table
    int t2 = tid - 327680; int t = t2 >> 5, i = t2 & 31;
    float theta = powf(10000.0f, -(float)i / 32.0f);
    float ang = (float)t * theta;
    ct[t2] = cosf(ang); st[t2] = sinf(ang);
  }
}

// ---------------------------------------------------------------- GEMM1: c_q/c_kv = x @ W1 (tile 128x256)
__global__ __launch_bounds__(512, 2) void k_gemm1(const float* __restrict__ X,
    const unsigned short* __restrict__ Bt, unsigned short* __restrict__ Cq,
    unsigned short* __restrict__ Ckv) {
  __shared__ __align__(16) unsigned short Ash[128 * 72];
  __shared__ __align__(16) unsigned short Bsh[256 * 72];
  const int nt2 = blockIdx.x, mt = blockIdx.y;
  const int tid = threadIdx.x;
  const int l = tid & 63, wv = tid >> 6, li = l & 15, g = l >> 4;
  const int wm = wv >> 2, wn = wv & 3;
  const f32x4 zf = {0.f, 0.f, 0.f, 0.f};
  f32x4 acc[4][4];
#pragma unroll
  for (int i = 0; i < 4; ++i)
#pragma unroll
    for (int j = 0; j < 4; ++j) acc[i][j] = zf;
  for (int kb = 0; kb < 256; kb += 64) {
    __syncthreads();
#pragma unroll
    for (int it = 0; it < 4; ++it) {        // A: 128x64 f32 -> bf16
      int idx = it * 512 + tid;
      int row = idx >> 4, c4 = (idx & 15) << 2;
      f32x4 v = *reinterpret_cast<const f32x4*>(X + (size_t)(mt * 128 + row) * 256 + kb + c4);
      u16x4 u = { f2b(v.x), f2b(v.y), f2b(v.z), f2b(v.w) };
      *reinterpret_cast<u16x4*>(&Ash[row * 72 + c4]) = u;
    }
#pragma unroll
    for (int it = 0; it < 4; ++it) {        // B: 256 rows of W1t
      int idx = it * 512 + tid;
      int row = idx >> 3, c8 = (idx & 7) << 3;
      *reinterpret_cast<u16x8*>(&Bsh[row * 72 + c8]) =
        *reinterpret_cast<const u16x8*>(Bt + (size_t)(nt2 * 256 + row) * 256 + kb + c8);
    }
    __syncthreads();
#pragma unroll
    for (int kc = 0; kc < 2; ++kc) {
      bf16x8 a[4], b[4];
#pragma unroll
      for (int mf = 0; mf < 4; ++mf)
        a[mf] = *reinterpret_cast<const bf16x8*>(&Ash[(wm * 64 + mf * 16 + li) * 72 + kc * 32 + g * 8]);
#pragma unroll
      for (int nf = 0; nf < 4; ++nf)
        b[nf] = *reinterpret_cast<const bf16x8*>(&Bsh[(wn * 64 + nf * 16 + li) * 72 + kc * 32 + g * 8]);
#pragma unroll
      for (int mf = 0; mf < 4; ++mf)
#pragma unroll
        for (int nf = 0; nf < 4; ++nf)
          acc[mf][nf] = mfma16(a[mf], b[nf], acc[mf][nf]);
    }
  }
  unsigned short* C = nt2 ? Ckv : Cq;
#pragma unroll
  for (int mf = 0; mf < 4; ++mf)
#pragma unroll
    for (int nf = 0; nf < 4; ++nf)
#pragma unroll
      for (int r = 0; r < 4; ++r) {
        int row = mt * 128 + wm * 64 + mf * 16 + g * 4 + r;
        int col = wn * 64 + nf * 16 + li;
        C[(size_t)row * 256 + col] = f2b(acc[mf][nf][r]);
      }
}

// ---------------------------------------------------------------- GEMM2: q/k/v projections (+RoPE, +vt transpose)
__global__ __launch_bounds__(512, 2) void k_gemm2(const unsigned short* __restrict__ Cq,
    const unsigned short* __restrict__ Ckv,
    const unsigned short* __restrict__ Wqt, const unsigned short* __restrict__ Wkvt,
    unsigned short* __restrict__ q_ws, unsigned short* __restrict__ k_ws,
    float* __restrict__ kout, float* __restrict__ vout,
    unsigned short* __restrict__ vt,
    const float* __restrict__ ct, const float* __restrict__ st, int sel0) {
  __shared__ __align__(16) unsigned short Ash[128 * 72];
  __shared__ __align__(16) unsigned short Bsh[256 * 72];
  const int sel = sel0 + blockIdx.x, mt = blockIdx.y;   // 0=q 1=k 2=v
  const int tid = threadIdx.x;
  const int l = tid & 63, wv = tid >> 6, li = l & 15, g = l >> 4;
  const int wm = wv >> 2, wn = wv & 3;
  const unsigned short* Asrc = (sel == 0) ? Cq : Ckv;
  const unsigned short* Wt = (sel == 0) ? Wqt : Wkvt;
  const int wrow = (sel == 2) ? 256 : 0;
  const f32x4 zf = {0.f, 0.f, 0.f, 0.f};
  f32x4 acc[4][4];
#pragma unroll
  for (int i = 0; i < 4; ++i)
#pragma unroll
    for (int j = 0; j < 4; ++j) acc[i][j] = zf;
  for (int kb = 0; kb < 256; kb += 64) {
    __syncthreads();
#pragma unroll
    for (int it = 0; it < 2; ++it) {        // A: 128x64 bf16
      int idx = it * 512 + tid;
      int row = idx >> 3, c8 = (idx & 7) << 3;
      *reinterpret_cast<u16x8*>(&Ash[row * 72 + c8]) =
        *reinterpret_cast<const u16x8*>(Asrc + (size_t)(mt * 128 + row) * 256 + kb + c8);
    }
#pragma unroll
    for (int it = 0; it < 4; ++it) {        // B: 256 rows
      int idx = it * 512 + tid;
      int row = idx >> 3, c8 = (idx & 7) << 3;
      *reinterpret_cast<u16x8*>(&Bsh[row * 72 + c8]) =
        *reinterpret_cast<const u16x8*>(Wt + (size_t)(wrow + row) * 256 + kb + c8);
    }
    __syncthreads();
#pragma unroll
    for (int kc = 0; kc < 2; ++kc) {
      bf16x8 a[4], b[4];
#pragma unroll
      for (int mf = 0; mf < 4; ++mf)
        a[mf] = *reinterpret_cast<const bf16x8*>(&Ash[(wm * 64 + mf * 16 + li) * 72 + kc * 32 + g * 8]);
#pragma unroll
      for (int nf = 0; nf < 4; ++nf)
        b[nf] = *reinterpret_cast<const bf16x8*>(&Bsh[(wn * 64 + nf * 16 + li) * 72 + kc * 32 + g * 8]);
#pragma unroll
      for (int mf = 0; mf < 4; ++mf)
#pragma unroll
        for (int nf = 0; nf < 4; ++nf)
          acc[mf][nf] = mfma16(a[mf], b[nf], acc[mf][nf]);
    }
  }
  // fused RoPE on local cols 192..255 (wn==3) for q (sel 0) and k (sel 1)
  if (sel < 2 && wn == 3) {
#pragma unroll
    for (int mf = 0; mf < 4; ++mf)
#pragma unroll
      for (int nf = 0; nf < 4; ++nf)
#pragma unroll
        for (int r = 0; r < 4; ++r) {
          float v = acc[mf][nf][r];
          float other = __shfl_xor(v, 1);
          int t = (mt * 128 + wm * 64 + mf * 16 + g * 4 + r) & 2047;
          int i = nf * 8 + (li >> 1);
          float c = ct[t * 32 + i], s = st[t * 32 + i];
          acc[mf][nf][r] = (li & 1) ? (other * s + v * c) : (v * c - other * s);
        }
  }
#pragma unroll
  for (int mf = 0; mf < 4; ++mf)
#pragma unroll
    for (int nf = 0; nf < 4; ++nf) {
      int cl = wn * 64 + nf * 16 + li;     // 0..255
#pragma unroll
      for (int r = 0; r < 4; ++r) {
        int row = mt * 128 + wm * 64 + mf * 16 + g * 4 + r;
        float val = acc[mf][nf][r];
        if (sel == 0) {
          q_ws[(size_t)row * 256 + cl] = f2b(val);
        } else if (sel == 1) {
          k_ws[(size_t)row * 256 + cl] = f2b(val);
          kout[(size_t)row * 256 + cl] = val;
        } else {
          vout[(size_t)row * 256 + cl] = val;
        }
      }
    }
  // sel==2: transposed bf16 write of this 128x256 tile into vt[b][d][t] via LDS bounce
  if (sel == 2) {
    const int batch = mt >> 4, tbase = (mt & 15) * 128;
#pragma unroll
    for (int h = 0; h < 2; ++h) {
      __syncthreads();
      if (wm == h) {
#pragma unroll
        for (int mf = 0; mf < 4; ++mf)
#pragma unroll
          for (int nf = 0; nf < 4; ++nf)
#pragma unroll
            for (int r = 0; r < 4; ++r) {
              int lr = mf * 16 + g * 4 + r;                  // 0..63
              int col = wn * 64 + nf * 16 + li;
              Bsh[lr * 258 + col] = f2b(acc[mf][nf][r]);
            }
      }
      __syncthreads();
#pragma unroll
      for (int it2 = 0; it2 < 8; ++it2) {
        int idx = it2 * 512 + tid;
        int d = idx >> 4, tq = (idx & 15) << 2;
        u16x4 pk = { Bsh[(tq + 0) * 258 + d], Bsh[(tq + 1) * 258 + d],
                     Bsh[(tq + 2) * 258 + d], Bsh[(tq + 3) * 258 + d] };
        *reinterpret_cast<u16x4*>(vt + ((size_t)batch * 256 + d) * 2048 + tbase + h * 64 + tq) = pk;
      }
    }
  }
}

// ---------------------------------------------------------------- flash attention v6
// 256 thr = 4 waves, M=32 q-rows/wave, Q-tile 128, KV-tile 64, full D=256.
// Single-buffered K/V (LDS 72KB -> 2 blocks/CU, 2 waves/SIMD). Phase-split staging:
// STAGE_K(j+1) issued post-QK barrier (covered by softmax+PV); STAGE_V(j+1) issued
// post-PV barrier (covered by next QK). Each __syncthreads vmcnt-drain has compute cover.
// grid(32 b, 16 yy): qt perm -> co-resident pair does uniform 34 iters; XCD pin = b%8.
__global__ __launch_bounds__(256, 2) void k_attn(
    const unsigned short* __restrict__ q_ws, const unsigned short* __restrict__ k_ws,
    const unsigned short* __restrict__ vt_ws, float* __restrict__ out) {
  __shared__ __align__(16) unsigned short Ksh[64 * 256];   // 32KB chunk-swizzled
  __shared__ __align__(16) unsigned short Vsh[256 * 64];   // 32KB chunk-swizzled
  __shared__ __align__(16) unsigned short Psh[4][1024];    // per-wave 32q x 32kk half (8KB)
  const int b = blockIdx.x;
  const int yy = blockIdx.y;
  const int qt = (yy < 8) ? (15 - 2 * yy) : (2 * (yy - 8));
  const int tid = threadIdx.x;
  const int l = tid & 63, wv = tid >> 6, li = l & 15, g = l >> 4;
  const f32x4 zf = {0.f, 0.f, 0.f, 0.f};

  u16x8 ones_u = {0x3F80, 0x3F80, 0x3F80, 0x3F80, 0x3F80, 0x3F80, 0x3F80, 0x3F80};
  bf16x8 ones = *reinterpret_cast<bf16x8*>(&ones_u);

  const unsigned short* kbase = k_ws + (size_t)b * 2048 * 256;
  const unsigned short* vbase = vt_ws + (size_t)b * 256 * 2048;

  // K tile 64x256: 2048 chunks, 8 rounds; LDS linear, source col pre-XOR'd.
#define STAGE_K(t)                                                                    \
  {                                                                                   \
    const unsigned short* ks_ = kbase + (size_t)(t) * 64 * 256;                       \
    _Pragma("unroll")                                                                 \
    for (int rnd = 0; rnd < 8; ++rnd) {                                               \
      int chunk = rnd * 256 + tid;                                                    \
      int row = chunk >> 5, pc = chunk & 31;                                          \
      gl16(ks_ + (size_t)row * 256 + ((pc ^ (row & 7)) << 3),                         \
           &Ksh[(size_t)(rnd * 256 + wv * 64) * 8]);                                  \
    }                                                                                 \
  }
  // V tile 256x64 d-major: 2048 chunks, 8 rounds.
#define STAGE_V(t)                                                                    \
  {                                                                                   \
    const unsigned short* vs_ = vbase + (size_t)(t) * 64;                             \
    _Pragma("unroll")                                                                 \
    for (int rnd = 0; rnd < 8; ++rnd) {                                               \
      int chunk = rnd * 256 + tid;                                                    \
      int d = chunk >> 3, pc = chunk & 7;                                             \
      gl16(vs_ + (size_t)d * 2048 + ((pc ^ (d & 7)) << 3),                            \
           &Vsh[(size_t)(rnd * 256 + wv * 64) * 8]);                                  \
    }                                                                                 \
  }

  const int wq0 = qt * 128 + wv * 32;
  bf16x8 qf[2][8];
#pragma unroll
  for (int mf = 0; mf < 2; ++mf) {
    const unsigned short* qp = q_ws + ((size_t)b * 2048 + wq0 + mf * 16 + li) * 256;
#pragma unroll
    for (int kc = 0; kc < 8; ++kc)
      qf[mf][kc] = *reinterpret_cast<const bf16x8*>(qp + kc * 32 + g * 8);
  }

  f32x4 o[2][16];
#pragma unroll
  for (int i = 0; i < 2; ++i)
#pragma unroll
    for (int j2 = 0; j2 < 16; ++j2) o[i][j2] = zf;
  f32x4 ol[2] = {zf, zf};

  const int nj = 2 * qt + 2;
  STAGE_K(0);
  STAGE_V(0);
  __syncthreads();                            // drains prologue loads

  for (int j = 0; j < nj; ++j) {
    const bool active = (j * 64 <= wq0 + 31);
    f32x4 s[2][4];
#pragma unroll
    for (int mf = 0; mf < 2; ++mf)
#pragma unroll
      for (int nf = 0; nf < 4; ++nf) s[mf][nf] = zf;

    if (active) {                             // QK^T: 32 q rows x 64 k rows
      __builtin_amdgcn_s_setprio(1);
#pragma unroll
      for (int kc = 0; kc < 8; ++kc) {
        int pc = (kc * 4 + g) ^ (li & 7);
#pragma unroll
        for (int nf = 0; nf < 4; ++nf) {
          bf16x8 bk = *reinterpret_cast<const bf16x8*>(&Ksh[(nf * 16 + li) * 256 + pc * 8]);
          s[0][nf] = mfma16(qf[0][kc], bk, s[0][nf]);
          s[1][nf] = mfma16(qf[1][kc], bk, s[1][nf]);
        }
      }
      __builtin_amdgcn_s_setprio(0);
    }
    __syncthreads();                          // all waves done reading Ksh
    if (j + 1 < nj) STAGE_K(j + 1);           // K loads fly under softmax+PV

    if (active) {
      const bool needmask = (j * 64 + 63) >= wq0;
#pragma unroll
      for (int h = 0; h < 2; ++h) {           // split-P halves
#pragma unroll
        for (int mf = 0; mf < 2; ++mf)
#pragma unroll
          for (int r = 0; r < 4; ++r) {
            const int q = mf * 16 + g * 4 + r;       // 0..31 wave-local
#pragma unroll
            for (int nf2 = 0; nf2 < 2; ++nf2) {
              const int nf = h * 2 + nf2;
              float pv = __expf(__builtin_fmaf(s[mf][nf][r], 0.0625f, -8.0f));
              if (needmask) {
                int kg = j * 64 + nf * 16 + li;      // global kv index
                if (kg > wq0 + q) pv = 0.f;
              }
              int kkl = nf2 * 16 + li;
              Psh[wv][q * 32 + (((kkl >> 3) ^ (q & 3)) << 3) + (kkl & 7)] = f2b(pv);
            }
          }
        bf16x8 pa0 = *reinterpret_cast<const bf16x8*>(&Psh[wv][li * 32 + ((g ^ (li & 3)) << 3)]);
        bf16x8 pa1 = *reinterpret_cast<const bf16x8*>(&Psh[wv][(16 + li) * 32 + ((g ^ (li & 3)) << 3)]);
        __builtin_amdgcn_s_setprio(1);
        ol[0] = mfma16(pa0, ones, ol[0]);
        ol[1] = mfma16(pa1, ones, ol[1]);
        const int pcv = (h * 4 + g) ^ (li & 7);
#pragma unroll
        for (int nfd = 0; nfd < 16; ++nfd) {
          bf16x8 bv = *reinterpret_cast<const bf16x8*>(&Vsh[(nfd * 16 + li) * 64 + pcv * 8]);
          o[0][nfd] = mfma16(pa0, bv, o[0][nfd]);
          o[1][nfd] = mfma16(pa1, bv, o[1][nfd]);
        }
        __builtin_amdgcn_s_setprio(0);
      }
    }
    __syncthreads();                          // all done reading Vsh + drains K(j+1)
    if (j + 1 < nj) STAGE_V(j + 1);           // V loads fly under next QK
  }

  // epilogue: 32 rows x 256 cols
#pragma unroll
  for (int mf = 0; mf < 2; ++mf)
#pragma unroll
    for (int r = 0; r < 4; ++r) {
      float inv = 1.0f / ol[mf][r];
      int qrow = wq0 + mf * 16 + g * 4 + r;
      float* op = out + ((size_t)b * 2048 + qrow) * 256;
#pragma unroll
      for (int nfd = 0; nfd < 16; ++nfd)
        op[nfd * 16 + li] = o[mf][nfd][r] * inv;
    }
#undef STAGE_K
#undef STAGE_V
}

// ---------------------------------------------------------------- launch
extern "C" void kernel_launch(void* const* d_in, const int* in_sizes, int n_in,
                              void* d_out, int out_size, void* d_ws, size_t ws_size,
                              hipStream_t stream) {
  const float* x        = (const float*)d_in[0];
  const float* Wq_comp  = (const float*)d_in[1];
  const float* Wkv_comp = (const float*)d_in[2];
  const float* Wqc      = (const float*)d_in[3];
  const float* Wqr      = (const float*)d_in[4];
  const float* Wkc      = (const float*)d_in[5];
  const float* Wkr      = (const float*)d_in[6];
  const float* Wv       = (const float*)d_in[7];

  float* out  = (float*)d_out;            // [32][2048][256]
  float* kout = out + 16777216;           // k output (f32)
  float* vout = out + 33554432;           // v output (f32)

  if (ws_size < 135397376u) return;

  char* ws = (char*)d_ws;
  unsigned short* c_q  = (unsigned short*)(ws);              // 32MB (vt aliases after q done)
  unsigned short* vt   = (unsigned short*)(ws);              // [32][256][2048] bf16 (32MB)
  unsigned short* c_kv = (unsigned short*)(ws + 33554432);   // 32MB
  unsigned short* q_ws = (unsigned short*)(ws + 67108864);   // 32MB
  unsigned short* k_ws = (unsigned short*)(ws + 100663296);  // 32MB
  unsigned short* W1t  = (unsigned short*)(ws + 134217728);  // 512x256
  unsigned short* Wqt  = W1t + 131072;                       // 256x256
  unsigned short* Wkvt = Wqt + 65536;                        // 512x256
  float* ct = (float*)(Wkvt + 131072);                       // 2048x32
  float* st = ct + 65536;

  k_prep<<<1536, 256, 0, stream>>>(Wq_comp, Wkv_comp, Wqc, Wqr, Wkc, Wkr, Wv,
                                   W1t, Wqt, Wkvt, ct, st);
  k_gemm1<<<dim3(2, 512), 512, 0, stream>>>(x, W1t, c_q, c_kv);
  // q and k first (read c_q/c_kv); then v (reads only c_kv, writes vt over c_q)
  k_gemm2<<<dim3(2, 512), 512, 0, stream>>>(c_q, c_kv, Wqt, Wkvt, q_ws, k_ws,
                                            kout, vout, vt, ct, st, 0);
  k_gemm2<<<dim3(1, 512), 512, 0, stream>>>(c_q, c_kv, Wqt, Wkvt, q_ws, k_ws,
                                            kout, vout, vt, ct, st, 2);
  k_attn<<<dim3(32, 16), 256, 0, stream>>>(q_ws, k_ws, vt, out);
}

// Round 7
// 338.880 us; speedup vs baseline: 1.4729x; 1.4729x over previous
//
#include <hip/hip_runtime.h>

typedef float  f32x4  __attribute__((ext_vector_type(4)));
typedef __bf16 bf16x8 __attribute__((ext_vector_type(8)));
typedef unsigned short u16x8 __attribute__((ext_vector_type(8)));
typedef unsigned short u16x4 __attribute__((ext_vector_type(4)));

#define DEV static __device__ __forceinline__

DEV unsigned short f2b(float f) {            // f32 -> bf16 (RNE)
  unsigned int u = __float_as_uint(f);
  u += 0x7fffu + ((u >> 16) & 1u);
  return (unsigned short)(u >> 16);
}
DEV float b2f(unsigned short h) { return __uint_as_float(((unsigned int)h) << 16); }

DEV f32x4 mfma16(bf16x8 a, bf16x8 b, f32x4 c) {
  return __builtin_amdgcn_mfma_f32_16x16x32_bf16(a, b, c, 0, 0, 0);
}

// ---------------------------------------------------------------- prep
__global__ __launch_bounds__(256) void k_prep(
    const float* __restrict__ Wq_comp, const float* __restrict__ Wkv_comp,
    const float* __restrict__ Wqc, const float* __restrict__ Wqr,
    const float* __restrict__ Wkc, const float* __restrict__ Wkr,
    const float* __restrict__ Wv,
    unsigned short* __restrict__ W1t, unsigned short* __restrict__ Wqt,
    unsigned short* __restrict__ Wkvt, float* __restrict__ ct, float* __restrict__ st) {
  int tid = blockIdx.x * 256 + threadIdx.x;
  if (tid < 131072) {                       // W1t
    int n = tid >> 8, k = tid & 255;
    float v = (n < 256) ? Wq_comp[k * 256 + n] : Wkv_comp[k * 256 + (n - 256)];
    W1t[tid] = f2b(v);
  } else if (tid < 196608) {                // Wqt
    int t2 = tid - 131072; int n = t2 >> 8, k = t2 & 255;
    float v = (n < 192) ? Wqc[k * 192 + n] : Wqr[k * 64 + (n - 192)];
    Wqt[t2] = f2b(v);
  } else if (tid < 327680) {                // Wkvt
    int t2 = tid - 196608; int n = t2 >> 8, k = t2 & 255;
    float v = (n < 192) ? Wkc[k * 192 + n]
             : (n < 256) ? Wkr[k * 64 + (n - 192)] : Wv[k * 256 + (n - 256)];
    Wkvt[t2] = f2b(v);
  } else if (tid < 393216) {                // rope table
    int t2 = tid - 327680; int t = t2 >> 5, i = t2 & 31;
    float theta = powf(10000.0f, -(float)i / 32.0f);
    float ang = (float)t * theta;
    ct[t2] = cosf(ang); st[t2] = sinf(ang);
  }
}

// ---------------------------------------------------------------- GEMM1: c_q/c_kv = x @ W1 (tile 128x256)
__global__ __launch_bounds__(512, 2) void k_gemm1(const float* __restrict__ X,
    const unsigned short* __restrict__ Bt, unsigned short* __restrict__ Cq,
    unsigned short* __restrict__ Ckv) {
  __shared__ __align__(16) unsigned short Ash[128 * 72];
  __shared__ __align__(16) unsigned short Bsh[256 * 72];
  const int nt2 = blockIdx.x, mt = blockIdx.y;
  const int tid = threadIdx.x;
  const int l = tid & 63, wv = tid >> 6, li = l & 15, g = l >> 4;
  const int wm = wv >> 2, wn = wv & 3;
  const f32x4 zf = {0.f, 0.f, 0.f, 0.f};
  f32x4 acc[4][4];
#pragma unroll
  for (int i = 0; i < 4; ++i)
#pragma unroll
    for (int j = 0; j < 4; ++j) acc[i][j] = zf;
  for (int kb = 0; kb < 256; kb += 64) {
    __syncthreads();
#pragma unroll
    for (int it = 0; it < 4; ++it) {        // A: 128x64 f32 -> bf16
      int idx = it * 512 + tid;
      int row = idx >> 4, c4 = (idx & 15) << 2;
      f32x4 v = *reinterpret_cast<const f32x4*>(X + (size_t)(mt * 128 + row) * 256 + kb + c4);
      u16x4 u = { f2b(v.x), f2b(v.y), f2b(v.z), f2b(v.w) };
      *reinterpret_cast<u16x4*>(&Ash[row * 72 + c4]) = u;
    }
#pragma unroll
    for (int it = 0; it < 4; ++it) {        // B: 256 rows of W1t
      int idx = it * 512 + tid;
      int row = idx >> 3, c8 = (idx & 7) << 3;
      *reinterpret_cast<u16x8*>(&Bsh[row * 72 + c8]) =
        *reinterpret_cast<const u16x8*>(Bt + (size_t)(nt2 * 256 + row) * 256 + kb + c8);
    }
    __syncthreads();
#pragma unroll
    for (int kc = 0; kc < 2; ++kc) {
      bf16x8 a[4], b[4];
#pragma unroll
      for (int mf = 0; mf < 4; ++mf)
        a[mf] = *reinterpret_cast<const bf16x8*>(&Ash[(wm * 64 + mf * 16 + li) * 72 + kc * 32 + g * 8]);
#pragma unroll
      for (int nf = 0; nf < 4; ++nf)
        b[nf] = *reinterpret_cast<const bf16x8*>(&Bsh[(wn * 64 + nf * 16 + li) * 72 + kc * 32 + g * 8]);
#pragma unroll
      for (int mf = 0; mf < 4; ++mf)
#pragma unroll
        for (int nf = 0; nf < 4; ++nf)
          acc[mf][nf] = mfma16(a[mf], b[nf], acc[mf][nf]);
    }
  }
  unsigned short* C = nt2 ? Ckv : Cq;
#pragma unroll
  for (int mf = 0; mf < 4; ++mf)
#pragma unroll
    for (int nf = 0; nf < 4; ++nf)
#pragma unroll
      for (int r = 0; r < 4; ++r) {
        int row = mt * 128 + wm * 64 + mf * 16 + g * 4 + r;
        int col = wn * 64 + nf * 16 + li;
        C[(size_t)row * 256 + col] = f2b(acc[mf][nf][r]);
      }
}

// ---------------------------------------------------------------- GEMM2: q/k/v projections (+RoPE, +vt transpose)
__global__ __launch_bounds__(512, 2) void k_gemm2(const unsigned short* __restrict__ Cq,
    const unsigned short* __restrict__ Ckv,
    const unsigned short* __restrict__ Wqt, const unsigned short* __restrict__ Wkvt,
    unsigned short* __restrict__ q_ws, unsigned short* __restrict__ k_ws,
    float* __restrict__ kout, float* __restrict__ vout,
    unsigned short* __restrict__ vt,
    const float* __restrict__ ct, const float* __restrict__ st, int sel0) {
  __shared__ __align__(16) unsigned short Ash[128 * 72];
  __shared__ __align__(16) unsigned short Bsh[256 * 72];
  const int sel = sel0 + blockIdx.x, mt = blockIdx.y;   // 0=q 1=k 2=v
  const int tid = threadIdx.x;
  const int l = tid & 63, wv = tid >> 6, li = l & 15, g = l >> 4;
  const int wm = wv >> 2, wn = wv & 3;
  const unsigned short* Asrc = (sel == 0) ? Cq : Ckv;
  const unsigned short* Wt = (sel == 0) ? Wqt : Wkvt;
  const int wrow = (sel == 2) ? 256 : 0;
  const f32x4 zf = {0.f, 0.f, 0.f, 0.f};
  f32x4 acc[4][4];
#pragma unroll
  for (int i = 0; i < 4; ++i)
#pragma unroll
    for (int j = 0; j < 4; ++j) acc[i][j] = zf;
  for (int kb = 0; kb < 256; kb += 64) {
    __syncthreads();
#pragma unroll
    for (int it = 0; it < 2; ++it) {        // A: 128x64 bf16
      int idx = it * 512 + tid;
      int row = idx >> 3, c8 = (idx & 7) << 3;
      *reinterpret_cast<u16x8*>(&Ash[row * 72 + c8]) =
        *reinterpret_cast<const u16x8*>(Asrc + (size_t)(mt * 128 + row) * 256 + kb + c8);
    }
#pragma unroll
    for (int it = 0; it < 4; ++it) {        // B: 256 rows
      int idx = it * 512 + tid;
      int row = idx >> 3, c8 = (idx & 7) << 3;
      *reinterpret_cast<u16x8*>(&Bsh[row * 72 + c8]) =
        *reinterpret_cast<const u16x8*>(Wt + (size_t)(wrow + row) * 256 + kb + c8);
    }
    __syncthreads();
#pragma unroll
    for (int kc = 0; kc < 2; ++kc) {
      bf16x8 a[4], b[4];
#pragma unroll
      for (int mf = 0; mf < 4; ++mf)
        a[mf] = *reinterpret_cast<const bf16x8*>(&Ash[(wm * 64 + mf * 16 + li) * 72 + kc * 32 + g * 8]);
#pragma unroll
      for (int nf = 0; nf < 4; ++nf)
        b[nf] = *reinterpret_cast<const bf16x8*>(&Bsh[(wn * 64 + nf * 16 + li) * 72 + kc * 32 + g * 8]);
#pragma unroll
      for (int mf = 0; mf < 4; ++mf)
#pragma unroll
        for (int nf = 0; nf < 4; ++nf)
          acc[mf][nf] = mfma16(a[mf], b[nf], acc[mf][nf]);
    }
  }
  // fused RoPE on local cols 192..255 (wn==3) for q (sel 0) and k (sel 1)
  if (sel < 2 && wn == 3) {
#pragma unroll
    for (int mf = 0; mf < 4; ++mf)
#pragma unroll
      for (int nf = 0; nf < 4; ++nf)
#pragma unroll
        for (int r = 0; r < 4; ++r) {
          float v = acc[mf][nf][r];
          float other = __shfl_xor(v, 1);
          int t = (mt * 128 + wm * 64 + mf * 16 + g * 4 + r) & 2047;
          int i = nf * 8 + (li >> 1);
          float c = ct[t * 32 + i], s = st[t * 32 + i];
          acc[mf][nf][r] = (li & 1) ? (other * s + v * c) : (v * c - other * s);
        }
  }
#pragma unroll
  for (int mf = 0; mf < 4; ++mf)
#pragma unroll
    for (int nf = 0; nf < 4; ++nf) {
      int cl = wn * 64 + nf * 16 + li;     // 0..255
#pragma unroll
      for (int r = 0; r < 4; ++r) {
        int row = mt * 128 + wm * 64 + mf * 16 + g * 4 + r;
        float val = acc[mf][nf][r];
        if (sel == 0) {
          q_ws[(size_t)row * 256 + cl] = f2b(val);
        } else if (sel == 1) {
          k_ws[(size_t)row * 256 + cl] = f2b(val);
          kout[(size_t)row * 256 + cl] = val;
        } else {
          vout[(size_t)row * 256 + cl] = val;
        }
      }
    }
  // sel==2: transposed bf16 write of this 128x256 tile into vt[b][d][t] via LDS bounce
  if (sel == 2) {
    const int batch = mt >> 4, tbase = (mt & 15) * 128;
#pragma unroll
    for (int h = 0; h < 2; ++h) {
      __syncthreads();
      if (wm == h) {
#pragma unroll
        for (int mf = 0; mf < 4; ++mf)
#pragma unroll
          for (int nf = 0; nf < 4; ++nf)
#pragma unroll
            for (int r = 0; r < 4; ++r) {
              int lr = mf * 16 + g * 4 + r;                  // 0..63
              int col = wn * 64 + nf * 16 + li;
              Bsh[lr * 258 + col] = f2b(acc[mf][nf][r]);
            }
      }
      __syncthreads();
#pragma unroll
      for (int it2 = 0; it2 < 8; ++it2) {
        int idx = it2 * 512 + tid;
        int d = idx >> 4, tq = (idx & 15) << 2;
        u16x4 pk = { Bsh[(tq + 0) * 258 + d], Bsh[(tq + 1) * 258 + d],
                     Bsh[(tq + 2) * 258 + d], Bsh[(tq + 3) * 258 + d] };
        *reinterpret_cast<u16x4*>(vt + ((size_t)batch * 256 + d) * 2048 + tbase + h * 64 + tq) = pk;
      }
    }
  }
}

// ---------------------------------------------------------------- flash attention v7 (= R3 structure + KV-128 staging)
// 512 thr = 8 waves x 16 q-rows, Q-tile 128, full D=256. Reg-staged double buffer
// (R3-proven): LDS single buffer, next tile prefetched into VGPRs during compute.
// KV staged 128 at a time (barriers/ds_write-burst halved vs R3), computed in two
// 64-kv sub-tiles with R3's exact inner body. Fixed-max softmax P=exp2(fma(s,c1,c2)).
// grid(32 b, 8 p): XCD pin = b%8; seg pairs (p, 15-p) -> uniform 17 staged tiles/block.
__global__ __launch_bounds__(512, 2) void k_attn(
    const unsigned short* __restrict__ q_ws, const unsigned short* __restrict__ k_ws,
    const unsigned short* __restrict__ vt_ws, float* __restrict__ out) {
  __shared__ __align__(16) unsigned short Ksh[128 * 256];   // 64KB [kr][d] swizzled
  __shared__ __align__(16) unsigned short Vsh[256 * 128];   // 64KB [d][kk] swizzled
  __shared__ __align__(16) unsigned short Psh[8][1024];     // per-wave [16 q][64 kk]
  const int b = blockIdx.x;
  const int p = blockIdx.y;
  const int tid = threadIdx.x;
  const int l = tid & 63, wv = tid >> 6, li = l & 15, g = l >> 4;
  const f32x4 zf = {0.f, 0.f, 0.f, 0.f};
  const float C1 = 0.09016844005556021f;    // log2(e)/16
  const float C2 = -11.541560327111707f;    // -8*log2(e)

  u16x8 ones_u = {0x3F80, 0x3F80, 0x3F80, 0x3F80, 0x3F80, 0x3F80, 0x3F80, 0x3F80};
  bf16x8 ones = *reinterpret_cast<bf16x8*>(&ones_u);

  const unsigned short* kbase = k_ws + (size_t)b * 2048 * 256;
  const unsigned short* vbase = vt_ws + (size_t)b * 256 * 2048;

  u16x8 kreg[8], vreg[8];
  // K chunk: rnd*512+tid -> row=chunk>>5 (0..127), pc=chunk&31. write pc^(row&7).
  // V chunk: rnd*512+tid -> d=chunk>>4 (0..255), pc=chunk&15. write pc^vswz(d),
  //   vswz(d) = (d&7) ^ (((d>>3)&1)<<3).
#define LOADREGS(t)                                                                   \
  {                                                                                   \
    const unsigned short* ks_ = kbase + (size_t)(t) * 128 * 256;                      \
    const unsigned short* vs_ = vbase + (size_t)(t) * 128;                            \
    _Pragma("unroll")                                                                 \
    for (int rnd = 0; rnd < 8; ++rnd) {                                               \
      int chunk = rnd * 512 + tid;                                                    \
      kreg[rnd] = *reinterpret_cast<const u16x8*>(ks_ + (size_t)(chunk >> 5) * 256 + (chunk & 31) * 8); \
    }                                                                                 \
    _Pragma("unroll")                                                                 \
    for (int rnd = 0; rnd < 8; ++rnd) {                                               \
      int chunk = rnd * 512 + tid;                                                    \
      vreg[rnd] = *reinterpret_cast<const u16x8*>(vs_ + (size_t)(chunk >> 4) * 2048 + (chunk & 15) * 8); \
    }                                                                                 \
  }

  for (int seg = 0; seg < 2; ++seg) {
    const int qt = seg ? (15 - p) : p;
    const int wq0 = qt * 128 + wv * 16;
    bf16x8 qf[8];
    const unsigned short* qp = q_ws + ((size_t)b * 2048 + wq0 + li) * 256;
#pragma unroll
    for (int kc = 0; kc < 8; ++kc)
      qf[kc] = *reinterpret_cast<const bf16x8*>(qp + kc * 32 + g * 8);

    f32x4 o[16];
#pragma unroll
    for (int i = 0; i < 16; ++i) o[i] = zf;
    f32x4 ol = zf;

    const int njj = qt + 1;                 // staged KV-128 tiles
    LOADREGS(0);

    for (int jj = 0; jj < njj; ++jj) {
      __syncthreads();                      // previous readers done
#pragma unroll
      for (int rnd = 0; rnd < 8; ++rnd) {   // K regs -> LDS (swizzled)
        int chunk = rnd * 512 + tid;
        int row = chunk >> 5, pc = chunk & 31;
        *reinterpret_cast<u16x8*>(&Ksh[row * 256 + (pc ^ (row & 7)) * 8]) = kreg[rnd];
      }
#pragma unroll
      for (int rnd = 0; rnd < 8; ++rnd) {   // V regs -> LDS (swizzled)
        int chunk = rnd * 512 + tid;
        int d = chunk >> 4, pc = chunk & 15;
        int vswz = (d & 7) ^ (((d >> 3) & 1) << 3);
        *reinterpret_cast<u16x8*>(&Vsh[d * 128 + (pc ^ vswz) * 8]) = vreg[rnd];
      }
      __syncthreads();
      if (jj + 1 < njj) LOADREGS(jj + 1);   // prefetch next tile into regs (covered by compute)

#pragma unroll
      for (int sub = 0; sub < 2; ++sub) {
        const int j = jj * 2 + sub;
        if (j * 64 > wq0 + 15) continue;    // wave fully masked for this sub-tile

        // QK^T: 16 q rows x 64 k rows
        f32x4 s[4];
#pragma unroll
        for (int nf = 0; nf < 4; ++nf) s[nf] = zf;
#pragma unroll
        for (int kc = 0; kc < 8; ++kc) {
          int pc = (kc * 4 + g) ^ (li & 7);
#pragma unroll
          for (int nf = 0; nf < 4; ++nf) {
            bf16x8 bk = *reinterpret_cast<const bf16x8*>(
                &Ksh[(sub * 64 + nf * 16 + li) * 256 + pc * 8]);
            s[nf] = mfma16(qf[kc], bk, s[nf]);
          }
        }
        // fixed-max softmax numerator, causal mask, pack (truncating bf16)
#pragma unroll
        for (int r = 0; r < 4; ++r) {
          const int q = g * 4 + r;          // local row 0..15
#pragma unroll
          for (int nf = 0; nf < 4; ++nf) {
            float pv = __builtin_amdgcn_exp2f(__builtin_fmaf(s[nf][r], C1, C2));
            int kg = j * 64 + nf * 16 + li;
            if (kg > wq0 + q) pv = 0.f;
            int kk = nf * 16 + li;
            int pcp = (kk >> 3) ^ (q & 7);
            Psh[wv][q * 64 + pcp * 8 + (kk & 7)] =
                (unsigned short)(__float_as_uint(pv) >> 16);
          }
        }
        // PV: O += P @ V ; l += P @ ones (per-wave P, no barrier needed)
#pragma unroll
        for (int kc2 = 0; kc2 < 2; ++kc2) {
          int pcp = (kc2 * 4 + g) ^ (li & 7);
          bf16x8 pa = *reinterpret_cast<const bf16x8*>(&Psh[wv][li * 64 + pcp * 8]);
          ol = mfma16(pa, ones, ol);
          const int cb = sub * 8 + kc2 * 4 + g;
#pragma unroll
          for (int nfd = 0; nfd < 16; ++nfd) {
            int d = nfd * 16 + li;
            int vswz = (d & 7) ^ (((d >> 3) & 1) << 3);
            bf16x8 bv = *reinterpret_cast<const bf16x8*>(&Vsh[d * 128 + (cb ^ vswz) * 8]);
            o[nfd] = mfma16(pa, bv, o[nfd]);
          }
        }
      }
    }

    // epilogue: 16 rows x 256 cols
#pragma unroll
    for (int r = 0; r < 4; ++r) {
      float inv = 1.0f / ol[r];
      int qrow = wq0 + g * 4 + r;
      float* op = out + ((size_t)b * 2048 + qrow) * 256;
#pragma unroll
      for (int nfd = 0; nfd < 16; ++nfd)
        op[nfd * 16 + li] = o[nfd][r] * inv;
    }
  }
#undef LOADREGS
}

// ---------------------------------------------------------------- launch
extern "C" void kernel_launch(void* const* d_in, const int* in_sizes, int n_in,
                              void* d_out, int out_size, void* d_ws, size_t ws_size,
                              hipStream_t stream) {
  const float* x        = (const float*)d_in[0];
  const float* Wq_comp  = (const float*)d_in[1];
  const float* Wkv_comp = (const float*)d_in[2];
  const float* Wqc      = (const float*)d_in[3];
  const float* Wqr      = (const float*)d_in[4];
  const float* Wkc      = (const float*)d_in[5];
  const float* Wkr      = (const float*)d_in[6];
  const float* Wv       = (const float*)d_in[7];

  float* out  = (float*)d_out;            // [32][2048][256]
  float* kout = out + 16777216;           // k output (f32)
  float* vout = out + 33554432;           // v output (f32)

  if (ws_size < 135397376u) return;

  char* ws = (char*)d_ws;
  unsigned short* c_q  = (unsigned short*)(ws);              // 32MB (vt aliases after q done)
  unsigned short* vt   = (unsigned short*)(ws);              // [32][256][2048] bf16 (32MB)
  unsigned short* c_kv = (unsigned short*)(ws + 33554432);   // 32MB
  unsigned short* q_ws = (unsigned short*)(ws + 67108864);   // 32MB
  unsigned short* k_ws = (unsigned short*)(ws + 100663296);  // 32MB
  unsigned short* W1t  = (unsigned short*)(ws + 134217728);  // 512x256
  unsigned short* Wqt  = W1t + 131072;                       // 256x256
  unsigned short* Wkvt = Wqt + 65536;                        // 512x256
  float* ct = (float*)(Wkvt + 131072);                       // 2048x32
  float* st = ct + 65536;

  k_prep<<<1536, 256, 0, stream>>>(Wq_comp, Wkv_comp, Wqc, Wqr, Wkc, Wkr, Wv,
                                   W1t, Wqt, Wkvt, ct, st);
  k_gemm1<<<dim3(2, 512), 512, 0, stream>>>(x, W1t, c_q, c_kv);
  // q and k first (read c_q/c_kv); then v (reads only c_kv, writes vt over c_q)
  k_gemm2<<<dim3(2, 512), 512, 0, stream>>>(c_q, c_kv, Wqt, Wkvt, q_ws, k_ws,
                                            kout, vout, vt, ct, st, 0);
  k_gemm2<<<dim3(1, 512), 512, 0, stream>>>(c_q, c_kv, Wqt, Wkvt, q_ws, k_ws,
                                            kout, vout, vt, ct, st, 2);
  k_attn<<<dim3(32, 8), 512, 0, stream>>>(q_ws, k_ws, vt, out);
}

// Round 8
// 313.162 us; speedup vs baseline: 1.5938x; 1.0821x over previous
//
#include <hip/hip_runtime.h>

typedef float  f32x4  __attribute__((ext_vector_type(4)));
typedef __bf16 bf16x8 __attribute__((ext_vector_type(8)));
typedef unsigned short u16x8 __attribute__((ext_vector_type(8)));
typedef unsigned short u16x4 __attribute__((ext_vector_type(4)));

#define DEV static __device__ __forceinline__

DEV unsigned short f2b(float f) {            // f32 -> bf16 (RNE)
  unsigned int u = __float_as_uint(f);
  u += 0x7fffu + ((u >> 16) & 1u);
  return (unsigned short)(u >> 16);
}
DEV float b2f(unsigned short h) { return __uint_as_float(((unsigned int)h) << 16); }

DEV f32x4 mfma16(bf16x8 a, bf16x8 b, f32x4 c) {
  return __builtin_amdgcn_mfma_f32_16x16x32_bf16(a, b, c, 0, 0, 0);
}

// ---------------------------------------------------------------- prep
__global__ __launch_bounds__(256) void k_prep(
    const float* __restrict__ Wq_comp, const float* __restrict__ Wkv_comp,
    const float* __restrict__ Wqc, const float* __restrict__ Wqr,
    const float* __restrict__ Wkc, const float* __restrict__ Wkr,
    const float* __restrict__ Wv,
    unsigned short* __restrict__ W1t, unsigned short* __restrict__ Wqt,
    unsigned short* __restrict__ Wkvt, float* __restrict__ ct, float* __restrict__ st) {
  int tid = blockIdx.x * 256 + threadIdx.x;
  if (tid < 131072) {                       // W1t
    int n = tid >> 8, k = tid & 255;
    float v = (n < 256) ? Wq_comp[k * 256 + n] : Wkv_comp[k * 256 + (n - 256)];
    W1t[tid] = f2b(v);
  } else if (tid < 196608) {                // Wqt
    int t2 = tid - 131072; int n = t2 >> 8, k = t2 & 255;
    float v = (n < 192) ? Wqc[k * 192 + n] : Wqr[k * 64 + (n - 192)];
    Wqt[t2] = f2b(v);
  } else if (tid < 327680) {                // Wkvt
    int t2 = tid - 196608; int n = t2 >> 8, k = t2 & 255;
    float v = (n < 192) ? Wkc[k * 192 + n]
             : (n < 256) ? Wkr[k * 64 + (n - 192)] : Wv[k * 256 + (n - 256)];
    Wkvt[t2] = f2b(v);
  } else if (tid < 393216) {                // rope table
    int t2 = tid - 327680; int t = t2 >> 5, i = t2 & 31;
    float theta = powf(10000.0f, -(float)i / 32.0f);
    float ang = (float)t * theta;
    ct[t2] = cosf(ang); st[t2] = sinf(ang);
  }
}

// ---------------------------------------------------------------- GEMM1: c_q/c_kv = x @ W1 (tile 128x256)
__global__ __launch_bounds__(512, 2) void k_gemm1(const float* __restrict__ X,
    const unsigned short* __restrict__ Bt, unsigned short* __restrict__ Cq,
    unsigned short* __restrict__ Ckv) {
  __shared__ __align__(16) unsigned short Ash[128 * 72];
  __shared__ __align__(16) unsigned short Bsh[256 * 72];
  const int nt2 = blockIdx.x, mt = blockIdx.y;
  const int tid = threadIdx.x;
  const int l = tid & 63, wv = tid >> 6, li = l & 15, g = l >> 4;
  const int wm = wv >> 2, wn = wv & 3;
  const f32x4 zf = {0.f, 0.f, 0.f, 0.f};
  f32x4 acc[4][4];
#pragma unroll
  for (int i = 0; i < 4; ++i)
#pragma unroll
    for (int j = 0; j < 4; ++j) acc[i][j] = zf;
  for (int kb = 0; kb < 256; kb += 64) {
    __syncthreads();
#pragma unroll
    for (int it = 0; it < 4; ++it) {        // A: 128x64 f32 -> bf16
      int idx = it * 512 + tid;
      int row = idx >> 4, c4 = (idx & 15) << 2;
      f32x4 v = *reinterpret_cast<const f32x4*>(X + (size_t)(mt * 128 + row) * 256 + kb + c4);
      u16x4 u = { f2b(v.x), f2b(v.y), f2b(v.z), f2b(v.w) };
      *reinterpret_cast<u16x4*>(&Ash[row * 72 + c4]) = u;
    }
#pragma unroll
    for (int it = 0; it < 4; ++it) {        // B: 256 rows of W1t
      int idx = it * 512 + tid;
      int row = idx >> 3, c8 = (idx & 7) << 3;
      *reinterpret_cast<u16x8*>(&Bsh[row * 72 + c8]) =
        *reinterpret_cast<const u16x8*>(Bt + (size_t)(nt2 * 256 + row) * 256 + kb + c8);
    }
    __syncthreads();
#pragma unroll
    for (int kc = 0; kc < 2; ++kc) {
      bf16x8 a[4], b[4];
#pragma unroll
      for (int mf = 0; mf < 4; ++mf)
        a[mf] = *reinterpret_cast<const bf16x8*>(&Ash[(wm * 64 + mf * 16 + li) * 72 + kc * 32 + g * 8]);
#pragma unroll
      for (int nf = 0; nf < 4; ++nf)
        b[nf] = *reinterpret_cast<const bf16x8*>(&Bsh[(wn * 64 + nf * 16 + li) * 72 + kc * 32 + g * 8]);
#pragma unroll
      for (int mf = 0; mf < 4; ++mf)
#pragma unroll
        for (int nf = 0; nf < 4; ++nf)
          acc[mf][nf] = mfma16(a[mf], b[nf], acc[mf][nf]);
    }
  }
  unsigned short* C = nt2 ? Ckv : Cq;
#pragma unroll
  for (int mf = 0; mf < 4; ++mf)
#pragma unroll
    for (int nf = 0; nf < 4; ++nf)
#pragma unroll
      for (int r = 0; r < 4; ++r) {
        int row = mt * 128 + wm * 64 + mf * 16 + g * 4 + r;
        int col = wn * 64 + nf * 16 + li;
        C[(size_t)row * 256 + col] = f2b(acc[mf][nf][r]);
      }
}

// ---------------------------------------------------------------- GEMM2: q/k/v projections (+RoPE, +vt transpose)
__global__ __launch_bounds__(512, 2) void k_gemm2(const unsigned short* __restrict__ Cq,
    const unsigned short* __restrict__ Ckv,
    const unsigned short* __restrict__ Wqt, const unsigned short* __restrict__ Wkvt,
    unsigned short* __restrict__ q_ws, unsigned short* __restrict__ k_ws,
    float* __restrict__ kout, float* __restrict__ vout,
    unsigned short* __restrict__ vt,
    const float* __restrict__ ct, const float* __restrict__ st, int sel0) {
  __shared__ __align__(16) unsigned short Ash[128 * 72];
  __shared__ __align__(16) unsigned short Bsh[256 * 72];
  const int sel = sel0 + blockIdx.x, mt = blockIdx.y;   // 0=q 1=k 2=v
  const int tid = threadIdx.x;
  const int l = tid & 63, wv = tid >> 6, li = l & 15, g = l >> 4;
  const int wm = wv >> 2, wn = wv & 3;
  const unsigned short* Asrc = (sel == 0) ? Cq : Ckv;
  const unsigned short* Wt = (sel == 0) ? Wqt : Wkvt;
  const int wrow = (sel == 2) ? 256 : 0;
  const f32x4 zf = {0.f, 0.f, 0.f, 0.f};
  f32x4 acc[4][4];
#pragma unroll
  for (int i = 0; i < 4; ++i)
#pragma unroll
    for (int j = 0; j < 4; ++j) acc[i][j] = zf;
  for (int kb = 0; kb < 256; kb += 64) {
    __syncthreads();
#pragma unroll
    for (int it = 0; it < 2; ++it) {        // A: 128x64 bf16
      int idx = it * 512 + tid;
      int row = idx >> 3, c8 = (idx & 7) << 3;
      *reinterpret_cast<u16x8*>(&Ash[row * 72 + c8]) =
        *reinterpret_cast<const u16x8*>(Asrc + (size_t)(mt * 128 + row) * 256 + kb + c8);
    }
#pragma unroll
    for (int it = 0; it < 4; ++it) {        // B: 256 rows
      int idx = it * 512 + tid;
      int row = idx >> 3, c8 = (idx & 7) << 3;
      *reinterpret_cast<u16x8*>(&Bsh[row * 72 + c8]) =
        *reinterpret_cast<const u16x8*>(Wt + (size_t)(wrow + row) * 256 + kb + c8);
    }
    __syncthreads();
#pragma unroll
    for (int kc = 0; kc < 2; ++kc) {
      bf16x8 a[4], b[4];
#pragma unroll
      for (int mf = 0; mf < 4; ++mf)
        a[mf] = *reinterpret_cast<const bf16x8*>(&Ash[(wm * 64 + mf * 16 + li) * 72 + kc * 32 + g * 8]);
#pragma unroll
      for (int nf = 0; nf < 4; ++nf)
        b[nf] = *reinterpret_cast<const bf16x8*>(&Bsh[(wn * 64 + nf * 16 + li) * 72 + kc * 32 + g * 8]);
#pragma unroll
      for (int mf = 0; mf < 4; ++mf)
#pragma unroll
        for (int nf = 0; nf < 4; ++nf)
          acc[mf][nf] = mfma16(a[mf], b[nf], acc[mf][nf]);
    }
  }
  // fused RoPE on local cols 192..255 (wn==3) for q (sel 0) and k (sel 1)
  if (sel < 2 && wn == 3) {
#pragma unroll
    for (int mf = 0; mf < 4; ++mf)
#pragma unroll
      for (int nf = 0; nf < 4; ++nf)
#pragma unroll
        for (int r = 0; r < 4; ++r) {
          float v = acc[mf][nf][r];
          float other = __shfl_xor(v, 1);
          int t = (mt * 128 + wm * 64 + mf * 16 + g * 4 + r) & 2047;
          int i = nf * 8 + (li >> 1);
          float c = ct[t * 32 + i], s = st[t * 32 + i];
          acc[mf][nf][r] = (li & 1) ? (other * s + v * c) : (v * c - other * s);
        }
  }
#pragma unroll
  for (int mf = 0; mf < 4; ++mf)
#pragma unroll
    for (int nf = 0; nf < 4; ++nf) {
      int cl = wn * 64 + nf * 16 + li;     // 0..255
#pragma unroll
      for (int r = 0; r < 4; ++r) {
        int row = mt * 128 + wm * 64 + mf * 16 + g * 4 + r;
        float val = acc[mf][nf][r];
        if (sel == 0) {
          q_ws[(size_t)row * 256 + cl] = f2b(val);
        } else if (sel == 1) {
          k_ws[(size_t)row * 256 + cl] = f2b(val);
          kout[(size_t)row * 256 + cl] = val;
        } else {
          vout[(size_t)row * 256 + cl] = val;
        }
      }
    }
  // sel==2: transposed bf16 write of this 128x256 tile into vt[b][d][t] via LDS bounce
  if (sel == 2) {
    const int batch = mt >> 4, tbase = (mt & 15) * 128;
#pragma unroll
    for (int h = 0; h < 2; ++h) {
      __syncthreads();
      if (wm == h) {
#pragma unroll
        for (int mf = 0; mf < 4; ++mf)
#pragma unroll
          for (int nf = 0; nf < 4; ++nf)
#pragma unroll
            for (int r = 0; r < 4; ++r) {
              int lr = mf * 16 + g * 4 + r;                  // 0..63
              int col = wn * 64 + nf * 16 + li;
              Bsh[lr * 258 + col] = f2b(acc[mf][nf][r]);
            }
      }
      __syncthreads();
#pragma unroll
      for (int it2 = 0; it2 < 8; ++it2) {
        int idx = it2 * 512 + tid;
        int d = idx >> 4, tq = (idx & 15) << 2;
        u16x4 pk = { Bsh[(tq + 0) * 258 + d], Bsh[(tq + 1) * 258 + d],
                     Bsh[(tq + 2) * 258 + d], Bsh[(tq + 3) * 258 + d] };
        *reinterpret_cast<u16x4*>(vt + ((size_t)batch * 256 + d) * 2048 + tbase + h * 64 + tq) = pk;
      }
    }
  }
}

// ---------------------------------------------------------------- flash attention v8
// R3's proven inner body, re-packaged for 2 blocks/CU + backfill:
// 256 thr = 4 waves x 16 q-rows (Q-tile 64), KV-tile 64, full D=256.
// Reg-staged double buffer (single LDS buffer + VGPR prefetch). LDS 72KB ->
// 2 independent blocks/CU (decoupled barriers overlap stage/drain with compute).
// grid(32 b, 32 y): qt = 31-y (longest-first, LPT backfill over 4 blocks/CU avg);
// wgid%8 = b%8 -> XCD-pinned L2 reuse. Fixed-max softmax P = exp2(fma(s,C1,C2)).
__global__ __launch_bounds__(256, 2) void k_attn(
    const unsigned short* __restrict__ q_ws, const unsigned short* __restrict__ k_ws,
    const unsigned short* __restrict__ vt_ws, float* __restrict__ out) {
  __shared__ __align__(16) unsigned short Ksh[64 * 256];   // 32KB [kr][d] swizzled
  __shared__ __align__(16) unsigned short Vsh[256 * 64];   // 32KB [d][kk] swizzled
  __shared__ __align__(16) unsigned short Psh[4][1024];    // per-wave [16 q][64 kk] (8KB)
  const int b = blockIdx.x;
  const int qt = 31 - (int)blockIdx.y;      // Q-64 tile index, longest first
  const int tid = threadIdx.x;
  const int l = tid & 63, wv = tid >> 6, li = l & 15, g = l >> 4;
  const f32x4 zf = {0.f, 0.f, 0.f, 0.f};
  const float C1 = 0.09016844005556021f;    // log2(e)/16
  const float C2 = -11.541560327111707f;    // -8*log2(e)

  u16x8 ones_u = {0x3F80, 0x3F80, 0x3F80, 0x3F80, 0x3F80, 0x3F80, 0x3F80, 0x3F80};
  bf16x8 ones = *reinterpret_cast<bf16x8*>(&ones_u);

  const unsigned short* kbase = k_ws + (size_t)b * 2048 * 256;
  const unsigned short* vbase = vt_ws + (size_t)b * 256 * 2048;

  u16x8 kreg[8], vreg[8];
  // K: chunk = rnd*256+tid -> row=chunk>>5 (0..63), pc=chunk&31 (32 chunks/row).
  // V: chunk = rnd*256+tid -> d=chunk>>3 (0..255), pc=chunk&7 (8 chunks/row).
#define LOADREGS(t)                                                                   \
  {                                                                                   \
    const unsigned short* ks_ = kbase + (size_t)(t) * 64 * 256;                       \
    const unsigned short* vs_ = vbase + (size_t)(t) * 64;                             \
    _Pragma("unroll")                                                                 \
    for (int rnd = 0; rnd < 8; ++rnd) {                                               \
      int chunk = rnd * 256 + tid;                                                    \
      kreg[rnd] = *reinterpret_cast<const u16x8*>(ks_ + (size_t)(chunk >> 5) * 256 + (chunk & 31) * 8); \
    }                                                                                 \
    _Pragma("unroll")                                                                 \
    for (int rnd = 0; rnd < 8; ++rnd) {                                               \
      int chunk = rnd * 256 + tid;                                                    \
      vreg[rnd] = *reinterpret_cast<const u16x8*>(vs_ + (size_t)(chunk >> 3) * 2048 + (chunk & 7) * 8); \
    }                                                                                 \
  }

  const int wq0 = qt * 64 + wv * 16;        // this wave's first q row
  bf16x8 qf[8];
  const unsigned short* qp = q_ws + ((size_t)b * 2048 + wq0 + li) * 256;
#pragma unroll
  for (int kc = 0; kc < 8; ++kc)
    qf[kc] = *reinterpret_cast<const bf16x8*>(qp + kc * 32 + g * 8);

  f32x4 o[16];
#pragma unroll
  for (int i = 0; i < 16; ++i) o[i] = zf;
  f32x4 ol = zf;

  const int nj = qt + 1;                    // KV-64 tiles (last = diagonal)
  LOADREGS(0);

  for (int j = 0; j < nj; ++j) {
    __syncthreads();                        // previous iteration's readers done
#pragma unroll
    for (int rnd = 0; rnd < 8; ++rnd) {     // K regs -> LDS (swizzled)
      int chunk = rnd * 256 + tid;
      int row = chunk >> 5, pc = chunk & 31;
      *reinterpret_cast<u16x8*>(&Ksh[row * 256 + (pc ^ (row & 7)) * 8]) = kreg[rnd];
    }
#pragma unroll
    for (int rnd = 0; rnd < 8; ++rnd) {     // V regs -> LDS (swizzled)
      int chunk = rnd * 256 + tid;
      int d = chunk >> 3, pc = chunk & 7;
      *reinterpret_cast<u16x8*>(&Vsh[d * 64 + (pc ^ (d & 7)) * 8]) = vreg[rnd];
    }
    __syncthreads();
    if (j + 1 < nj) LOADREGS(j + 1);        // prefetch next tile into regs

    // QK^T: 16 q rows x 64 k rows
    f32x4 s[4];
#pragma unroll
    for (int nf = 0; nf < 4; ++nf) s[nf] = zf;
#pragma unroll
    for (int kc = 0; kc < 8; ++kc) {
      int pc = (kc * 4 + g) ^ (li & 7);
#pragma unroll
      for (int nf = 0; nf < 4; ++nf) {
        bf16x8 bk = *reinterpret_cast<const bf16x8*>(&Ksh[(nf * 16 + li) * 256 + pc * 8]);
        s[nf] = mfma16(qf[kc], bk, s[nf]);
      }
    }
    // fixed-max softmax numerator, causal mask on diagonal tile, truncating pack
    const bool diag = (j == qt);
#pragma unroll
    for (int r = 0; r < 4; ++r) {
      const int q = g * 4 + r;              // local row 0..15
#pragma unroll
      for (int nf = 0; nf < 4; ++nf) {
        float pv = __builtin_amdgcn_exp2f(__builtin_fmaf(s[nf][r], C1, C2));
        if (diag && (j * 64 + nf * 16 + li) > (wq0 + q)) pv = 0.f;
        int kk = nf * 16 + li;
        int pcp = (kk >> 3) ^ (q & 7);
        Psh[wv][q * 64 + pcp * 8 + (kk & 7)] =
            (unsigned short)(__float_as_uint(pv) >> 16);
      }
    }
    // PV: O += P @ V ; l += P @ ones (per-wave P, no barrier needed)
#pragma unroll
    for (int kc2 = 0; kc2 < 2; ++kc2) {
      int pcp = (kc2 * 4 + g) ^ (li & 7);
      bf16x8 pa = *reinterpret_cast<const bf16x8*>(&Psh[wv][li * 64 + pcp * 8]);
      ol = mfma16(pa, ones, ol);
#pragma unroll
      for (int nfd = 0; nfd < 16; ++nfd) {
        int d = nfd * 16 + li;
        bf16x8 bv = *reinterpret_cast<const bf16x8*>(&Vsh[d * 64 + pcp * 8]);
        o[nfd] = mfma16(pa, bv, o[nfd]);
      }
    }
  }

  // epilogue: 16 rows x 256 cols
#pragma unroll
  for (int r = 0; r < 4; ++r) {
    float inv = 1.0f / ol[r];
    int qrow = wq0 + g * 4 + r;
    float* op = out + ((size_t)b * 2048 + qrow) * 256;
#pragma unroll
    for (int nfd = 0; nfd < 16; ++nfd)
      op[nfd * 16 + li] = o[nfd][r] * inv;
  }
#undef LOADREGS
}

// ---------------------------------------------------------------- launch
extern "C" void kernel_launch(void* const* d_in, const int* in_sizes, int n_in,
                              void* d_out, int out_size, void* d_ws, size_t ws_size,
                              hipStream_t stream) {
  const float* x        = (const float*)d_in[0];
  const float* Wq_comp  = (const float*)d_in[1];
  const float* Wkv_comp = (const float*)d_in[2];
  const float* Wqc      = (const float*)d_in[3];
  const float* Wqr      = (const float*)d_in[4];
  const float* Wkc      = (const float*)d_in[5];
  const float* Wkr      = (const float*)d_in[6];
  const float* Wv       = (const float*)d_in[7];

  float* out  = (float*)d_out;            // [32][2048][256]
  float* kout = out + 16777216;           // k output (f32)
  float* vout = out + 33554432;           // v output (f32)

  if (ws_size < 135397376u) return;

  char* ws = (char*)d_ws;
  unsigned short* c_q  = (unsigned short*)(ws);              // 32MB (vt aliases after q done)
  unsigned short* vt   = (unsigned short*)(ws);              // [32][256][2048] bf16 (32MB)
  unsigned short* c_kv = (unsigned short*)(ws + 33554432);   // 32MB
  unsigned short* q_ws = (unsigned short*)(ws + 67108864);   // 32MB
  unsigned short* k_ws = (unsigned short*)(ws + 100663296);  // 32MB
  unsigned short* W1t  = (unsigned short*)(ws + 134217728);  // 512x256
  unsigned short* Wqt  = W1t + 131072;                       // 256x256
  unsigned short* Wkvt = Wqt + 65536;                        // 512x256
  float* ct = (float*)(Wkvt + 131072);                       // 2048x32
  float* st = ct + 65536;

  k_prep<<<1536, 256, 0, stream>>>(Wq_comp, Wkv_comp, Wqc, Wqr, Wkc, Wkr, Wv,
                                   W1t, Wqt, Wkvt, ct, st);
  k_gemm1<<<dim3(2, 512), 512, 0, stream>>>(x, W1t, c_q, c_kv);
  // q and k first (read c_q/c_kv); then v (reads only c_kv, writes vt over c_q)
  k_gemm2<<<dim3(2, 512), 512, 0, stream>>>(c_q, c_kv, Wqt, Wkvt, q_ws, k_ws,
                                            kout, vout, vt, ct, st, 0);
  k_gemm2<<<dim3(1, 512), 512, 0, stream>>>(c_q, c_kv, Wqt, Wkvt, q_ws, k_ws,
                                            kout, vout, vt, ct, st, 2);
  k_attn<<<dim3(32, 32), 256, 0, stream>>>(q_ws, k_ws, vt, out);
}